// Round 14
// baseline (95.637 us; speedup 1.0000x reference)
//
#include <hip/hip_runtime.h>
#include <hip/hip_bf16.h>

// out[d,t] = (sum_j exp(s[t,j]) * u[j,d]) / (sum_j exp(s[t,j]))
// R14: 16 waves/CU inside ONE 1024-thread block, with the s-prefetch pipeline
// moved from VGPRs into LDS via global_load_lds (staging costs ~0 registers,
// so the body fits the 64-VGPR class the allocator forces on 1024-thread
// blocks — R5/R7 spilled because the register pipeline needed 48-64 VGPRs).
// 256 blocks x (half-D, 512 rows); B = 64KB LDS; ring-3 of 32KB s-tiles
// (160KB LDS total, 1 block/CU = 4 waves/SIMD by construction).
// Each wave stages EXACTLY its own 16 rows of each tile -> no cross-wave
// dependency -> ZERO barriers in the main loop; per-wave counted vmcnt(2)
// (vmcnt(6) at the two steps after panel-0's stores sit in the queue).
// 128B-row tile would be a 32-way bank conflict (G4): XOR-swizzle
// byte ^= (row&7)<<4 applied on the GLOBAL source (linear gll dest, rule #21)
// and on the read. Arithmetic bit-identical to R10/R13 -> absmax 0.00390625.

constexpr int T_DIM = 65536;
constexpr int J_DIM = 512;
constexpr int D_DIM = 128;
constexpr int KK_STEPS = 16;           // K-chunks per panel
constexpr int NSTEP = 32;              // 2 panels x 16
constexpr int NFRAG = 4;               // half of D
constexpr int BP_ELEMS = KK_STEPS * NFRAG * 64;   // 4096 s16x8 = 64KB

typedef __attribute__((ext_vector_type(4))) float  f32x4;
typedef __attribute__((ext_vector_type(8))) short  s16x8;
typedef __attribute__((ext_vector_type(8))) __bf16 bf16x8;

typedef const __attribute__((address_space(1))) unsigned int* gas_ptr;
typedef __attribute__((address_space(3))) unsigned int* las_ptr;

__device__ __forceinline__ short f2bf_rne(float f) {
    unsigned u = __builtin_bit_cast(unsigned, f);
    u += 0x7fffu + ((u >> 16) & 1u);   // round-to-nearest-even
    return (short)(u >> 16);
}

__global__ __launch_bounds__(1024) void c2q_main(const float* __restrict__ sm,
                                                 const float* __restrict__ u,
                                                 float* __restrict__ out) {
    __shared__ s16x8 bsh[BP_ELEMS];                           // 65536 B
    __shared__ __align__(16) unsigned char stile[3][256 * 128]; // 98304 B

    const int tid  = threadIdx.x;
    const int l    = tid & 63;
    const int w    = tid >> 6;          // wave 0..15
    const int lmod = l & 15;
    const int lh   = l >> 4;            // 0..3
    const int bid  = blockIdx.x;
    const int h    = bid >> 7;          // d-half (bid = h*128 + rg)
    const int rg   = bid & 127;         // row-group (512 rows)
    const int d0   = h * 64;

    // ---- B gather-fill from u (L2-resident), this block's d-half ----
#pragma unroll
    for (int it = 0; it < BP_ELEMS / 1024; ++it) {
        int e  = it * 1024 + tid;
        int d  = d0 + ((e >> 6) & (NFRAG - 1)) * 16 + (e & 15);
        int k0 = (e >> 8) * 32 + 8 * ((e >> 4) & 3);
        const float* up = u + (size_t)k0 * D_DIM + d;
        s16x8 o;
#pragma unroll
        for (int i = 0; i < 8; ++i)
            o[i] = f2bf_rne(up[(size_t)i * D_DIM]);
        bsh[e] = o;
    }
    __syncthreads();   // B visible to all; stages not yet issued

    // ---- staging geometry: wave w stages its OWN rows w*16..w*16+15 ----
    const int rsub = l >> 3;            // 0..7  (row within 8-row gll chunk)
    const int csub = l & 7;             // 0..7  (16B unit within 128B row)
    const unsigned swz_st = (unsigned)rsub << 4;
    const char* smb = (const char*)sm;
    // lane's global byte offset (panel 0, tk 0, j 0):
    const size_t stage_base = ((size_t)rg * 512 + w * 16 + rsub) * 2048
                              + (((unsigned)(csub * 16)) ^ swz_st);

#define STAGE(G)                                                              \
    {                                                                         \
        constexpr int p2_ = (G) >> 4, tk2_ = (G) & 15, b_ = (G) % 3;          \
        _Pragma("unroll")                                                     \
        for (int j = 0; j < 2; ++j) {                                         \
            const char* src_ = smb + stage_base + (size_t)p2_ * (256 * 2048)  \
                               + (size_t)j * (8 * 2048) + tk2_ * 128;         \
            __builtin_amdgcn_global_load_lds(                                 \
                (gas_ptr)(const void*)src_,                                   \
                (las_ptr)(void*)&stile[b_][(w * 16 + j * 8) * 128], 16, 0, 0);\
        }                                                                     \
    }

    STAGE(0)
    STAGE(1)

    // ---- compute geometry ----
    const int trow = w * 16 + lmod;                 // tile row this lane reads
    const unsigned swz_rd = (unsigned)(lmod & 7) << 4;
    const unsigned cA = ((unsigned)(lh * 32)) ^ swz_rd;
    const unsigned cB = ((unsigned)(lh * 32 + 16)) ^ swz_rd;

    f32x4 acc[NFRAG];
#pragma unroll
    for (int nf = 0; nf < NFRAG; ++nf) acc[nf] = (f32x4){0.f, 0.f, 0.f, 0.f};
    float den = 0.f;

#pragma unroll
    for (int g = 0; g < NSTEP; ++g) {
        // counted vmcnt: own stage-g done; never drain the pipeline.
        // steps 16/17: panel-0's 4 stores sit between stage-g and the wait
        // target in the in-order queue -> allow 6 outstanding.
        if (g == 16 || g == 17)      asm volatile("s_waitcnt vmcnt(6)" ::: "memory");
        else if (g == NSTEP - 1)     asm volatile("s_waitcnt vmcnt(0)" ::: "memory");
        else                         asm volatile("s_waitcnt vmcnt(2)" ::: "memory");
        __builtin_amdgcn_sched_barrier(0);

        if (g + 2 < NSTEP) {
            if (g + 2 == 2)  STAGE(2)   // constexpr-dispatch via unroll
            if (g + 2 == 3)  STAGE(3)
            if (g + 2 == 4)  STAGE(4)
            if (g + 2 == 5)  STAGE(5)
            if (g + 2 == 6)  STAGE(6)
            if (g + 2 == 7)  STAGE(7)
            if (g + 2 == 8)  STAGE(8)
            if (g + 2 == 9)  STAGE(9)
            if (g + 2 == 10) STAGE(10)
            if (g + 2 == 11) STAGE(11)
            if (g + 2 == 12) STAGE(12)
            if (g + 2 == 13) STAGE(13)
            if (g + 2 == 14) STAGE(14)
            if (g + 2 == 15) STAGE(15)
            if (g + 2 == 16) STAGE(16)
            if (g + 2 == 17) STAGE(17)
            if (g + 2 == 18) STAGE(18)
            if (g + 2 == 19) STAGE(19)
            if (g + 2 == 20) STAGE(20)
            if (g + 2 == 21) STAGE(21)
            if (g + 2 == 22) STAGE(22)
            if (g + 2 == 23) STAGE(23)
            if (g + 2 == 24) STAGE(24)
            if (g + 2 == 25) STAGE(25)
            if (g + 2 == 26) STAGE(26)
            if (g + 2 == 27) STAGE(27)
            if (g + 2 == 28) STAGE(28)
            if (g + 2 == 29) STAGE(29)
            if (g + 2 == 30) STAGE(30)
            if (g + 2 == 31) STAGE(31)
        }

        const unsigned char* tb = stile[g % 3];
        f32x4 s0 = *reinterpret_cast<const f32x4*>(tb + trow * 128 + cA);
        f32x4 s1 = *reinterpret_cast<const f32x4*>(tb + trow * 128 + cB);

        float e0 = __expf(s0[0]), e1 = __expf(s0[1]);
        float e2 = __expf(s0[2]), e3 = __expf(s0[3]);
        float e4 = __expf(s1[0]), e5 = __expf(s1[1]);
        float e6 = __expf(s1[2]), e7 = __expf(s1[3]);
        den += ((e0 + e1) + (e2 + e3)) + ((e4 + e5) + (e6 + e7));
        s16x8 a;
        a[0] = f2bf_rne(e0); a[1] = f2bf_rne(e1);
        a[2] = f2bf_rne(e2); a[3] = f2bf_rne(e3);
        a[4] = f2bf_rne(e4); a[5] = f2bf_rne(e5);
        a[6] = f2bf_rne(e6); a[7] = f2bf_rne(e7);
        bf16x8 av = __builtin_bit_cast(bf16x8, a);
        const int tk = g & 15;
#pragma unroll
        for (int nf = 0; nf < NFRAG; ++nf) {
            bf16x8 bv = __builtin_bit_cast(bf16x8, bsh[(tk * NFRAG + nf) * 64 + l]);
            acc[nf] = __builtin_amdgcn_mfma_f32_16x16x32_bf16(av, bv, acc[nf], 0, 0, 0);
        }

        if ((g & 15) == 15) {
            // ---- panel epilogue (p = g>>4): den-reduce, divide, store ----
            float dd = den;
            dd += __shfl_xor(dd, 16, 64);
            dd += __shfl_xor(dd, 32, 64);
            float inv[4];
#pragma unroll
            for (int r = 0; r < 4; ++r)
                inv[r] = 1.0f / __shfl(dd, 4 * lh + r, 64);
            const int rp = rg * 512 + (g >> 4) * 256 + w * 16;
#pragma unroll
            for (int nf = 0; nf < NFRAG; ++nf) {
                f32x4 v;
#pragma unroll
                for (int r = 0; r < 4; ++r) v[r] = acc[nf][r] * inv[r];
                *reinterpret_cast<f32x4*>(out + (size_t)(d0 + nf * 16 + lmod) * T_DIM
                                          + rp + 4 * lh) = v;
                acc[nf] = (f32x4){0.f, 0.f, 0.f, 0.f};
            }
            den = 0.f;
        }
    }
#undef STAGE
}

extern "C" void kernel_launch(void* const* d_in, const int* in_sizes, int n_in,
                              void* d_out, int out_size, void* d_ws, size_t ws_size,
                              hipStream_t stream) {
    const float* u = (const float*)d_in[0];   // (1, 512, 128) fp32
    const float* s = (const float*)d_in[1];   // (65536, 512) fp32
    float* out = (float*)d_out;               // (128, 65536) fp32

    c2q_main<<<2 * (T_DIM / 512), 1024, 0, stream>>>(s, u, out);
}

// Round 15
// 37.071 us; speedup vs baseline: 2.5798x; 2.5798x over previous
//
#include <hip/hip_runtime.h>
#include <hip/hip_bf16.h>

// out[d,t] = (sum_j exp(s[t,j]) * u[j,d]) / (sum_j exp(s[t,j]))
// Fused exp-GEMM, B staged in LDS once per block.
// R15 = R9's proven body/geometry (256 blocks x 512 threads, 1 block/CU, two
// sequential 128-row panels, rotating register prefetch, manual f2bf_rne,
// sched_barrier every iteration) with three safe upgrades:
//   1) PF_DEPTH 8 (slot = g&7): 16KB/wave in flight, no occupancy cost
//      (we are in the 2-wave/SIMD class either way).
//   2) B gather-fill unroll 8: more MLP during the prologue.
//   3) Nontemporal out stores: don't evict the L3-resident half of s
//      (R1 showed FETCH 66MB for a 128MB stream -> L3 retains ~half).
// Lesson bank: >512-thread blocks or concurrent 2-tile state => allocator
// forces 64 VGPR and spills (R5/R6/R7/R11/R14). D-split co-residency never
// materialized (R13). 512/(512,2) is the only performing class.

constexpr int T_DIM = 65536;
constexpr int J_DIM = 512;
constexpr int D_DIM = 128;
constexpr int KK_STEPS = J_DIM / 32;   // 16
constexpr int NFRAG = 8;               // 8 N-fragments covering D=128
constexpr int PF_DEPTH = 8;            // s-load prefetch depth (iterations)
constexpr int BP_ELEMS = KK_STEPS * NFRAG * 64;   // s16x8 elements = 8192 (128KB)

typedef __attribute__((ext_vector_type(4))) float  f32x4;
typedef __attribute__((ext_vector_type(8))) short  s16x8;
typedef __attribute__((ext_vector_type(8))) __bf16 bf16x8;

__device__ __forceinline__ short f2bf_rne(float f) {
    unsigned u = __builtin_bit_cast(unsigned, f);
    u += 0x7fffu + ((u >> 16) & 1u);   // round-to-nearest-even
    return (short)(u >> 16);
}

__global__ __launch_bounds__(512, 2) void c2q_main(const float* __restrict__ sm,
                                                   const float* __restrict__ u,
                                                   float* __restrict__ out) {
    __shared__ s16x8 bsh[BP_ELEMS];    // [kk][nf][lane] — 131072 bytes

    const int tid  = threadIdx.x;
    const int l    = tid & 63;
    const int w    = tid >> 6;        // wave 0..7
    const int lmod = l & 15;
    const int lh   = l >> 4;          // 0..3
    const int r0   = blockIdx.x * 256 + w * 16;  // panel-0 first t-row

    // A-fragment sources: lane holds row r0+lmod, k = kk*32 + 8*lh + i.
    const float* sp0 = sm + (size_t)(r0 + lmod) * J_DIM + lh * 8;
    const float* sp1 = sp0 + 128 * J_DIM;        // panel-1 (r0+128)

    // ---- prologue: prefetch global iterations 0..7 (panel 0, kk 0..7) ----
    f32x4 sbuf[PF_DEPTH][2];
#pragma unroll
    for (int p = 0; p < PF_DEPTH; ++p) {
        sbuf[p][0] = *reinterpret_cast<const f32x4*>(sp0 + p * 32);
        sbuf[p][1] = *reinterpret_cast<const f32x4*>(sp0 + p * 32 + 4);
    }

    // ---- B gather-fill straight from u (L2-resident, 256KB), once ----
#pragma unroll 8
    for (int it = 0; it < BP_ELEMS / 512; ++it) {
        int e  = it * 512 + tid;
        int d  = ((e >> 6) & (NFRAG - 1)) * 16 + (e & 15);
        int k0 = (e >> 9) * 32 + 8 * ((e >> 4) & 3);
        const float* up = u + (size_t)k0 * D_DIM + d;
        s16x8 o;
#pragma unroll
        for (int i = 0; i < 8; ++i)
            o[i] = f2bf_rne(up[(size_t)i * D_DIM]);
        bsh[e] = o;
    }
    __syncthreads();

#pragma unroll
    for (int p = 0; p < 2; ++p) {
        const int rp = r0 + p * 128;

        f32x4 acc[NFRAG];
#pragma unroll
        for (int nf = 0; nf < NFRAG; ++nf) acc[nf] = (f32x4){0.f, 0.f, 0.f, 0.f};
        float den = 0.f;

#pragma unroll
        for (int kk = 0; kk < KK_STEPS; ++kk) {
            const int g    = p * KK_STEPS + kk;      // global iteration 0..31
            const int slot = g & (PF_DEPTH - 1);     // compile-time constant
            f32x4 s0 = sbuf[slot][0];
            f32x4 s1 = sbuf[slot][1];
            // refill this slot for global iteration g+8 (possibly next panel)
            if (g + PF_DEPTH < 2 * KK_STEPS) {
                const int   f  = g + PF_DEPTH;
                const float* b = (f < KK_STEPS) ? sp0 : sp1;
                const int   tk = f & (KK_STEPS - 1);
                sbuf[slot][0] = *reinterpret_cast<const f32x4*>(b + tk * 32);
                sbuf[slot][1] = *reinterpret_cast<const f32x4*>(b + tk * 32 + 4);
            }
            float e0 = __expf(s0[0]), e1 = __expf(s0[1]);
            float e2 = __expf(s0[2]), e3 = __expf(s0[3]);
            float e4 = __expf(s1[0]), e5 = __expf(s1[1]);
            float e6 = __expf(s1[2]), e7 = __expf(s1[3]);
            den += ((e0 + e1) + (e2 + e3)) + ((e4 + e5) + (e6 + e7));
            s16x8 a;
            a[0] = f2bf_rne(e0); a[1] = f2bf_rne(e1);
            a[2] = f2bf_rne(e2); a[3] = f2bf_rne(e3);
            a[4] = f2bf_rne(e4); a[5] = f2bf_rne(e5);
            a[6] = f2bf_rne(e6); a[7] = f2bf_rne(e7);
            bf16x8 av = __builtin_bit_cast(bf16x8, a);
#pragma unroll
            for (int nf = 0; nf < NFRAG; ++nf) {
                bf16x8 bv = __builtin_bit_cast(bf16x8, bsh[(kk * NFRAG + nf) * 64 + l]);
                acc[nf] = __builtin_amdgcn_mfma_f32_16x16x32_bf16(av, bv, acc[nf], 0, 0, 0);
            }
            __builtin_amdgcn_sched_barrier(0);   // fence EVERY iteration (R9)
        }

        // den(l) holds row lmod's partial over k-chunk lh: reduce the 4 chunks.
        den += __shfl_xor(den, 16, 64);
        den += __shfl_xor(den, 32, 64);
        // C/D layout: col = lane&15 (-> d), row = 4*(lane>>4)+reg (-> t).
        float inv[4];
#pragma unroll
        for (int r = 0; r < 4; ++r)
            inv[r] = 1.0f / __shfl(den, 4 * lh + r, 64);

#pragma unroll
        for (int nf = 0; nf < NFRAG; ++nf) {
            f32x4 v;
#pragma unroll
            for (int r = 0; r < 4; ++r) v[r] = acc[nf][r] * inv[r];
            f32x4* dst = reinterpret_cast<f32x4*>(
                out + (size_t)(nf * 16 + lmod) * T_DIM + rp + 4 * lh);
            __builtin_nontemporal_store(v, dst);   // don't evict s from L3
        }
    }
}

extern "C" void kernel_launch(void* const* d_in, const int* in_sizes, int n_in,
                              void* d_out, int out_size, void* d_ws, size_t ws_size,
                              hipStream_t stream) {
    const float* u = (const float*)d_in[0];   // (1, 512, 128) fp32
    const float* s = (const float*)d_in[1];   // (65536, 512) fp32
    float* out = (float*)d_out;               // (128, 65536) fp32

    c2q_main<<<T_DIM / 256, 512, 0, stream>>>(s, u, out);
}